// Round 11
// baseline (3163.440 us; speedup 1.0000x reference)
//
#include <hip/hip_runtime.h>
#include <math.h>

typedef unsigned int u32;
typedef unsigned long long u64;

#define B_    8
#define C_    512
#define HW_   4096
#define NA    36864        // 4096*9 anchors per image
#define PRE_NMS  2000
#define POST_NMS 300

// output flat offsets (floats)
#define LOC_OFF   0
#define SC_OFF    1179648
#define ROIS_OFF  1769472
#define IDX_OFF   1779072
#define ANCH_OFF  1781472

// ---------------------------------------------------------------------------
// anchor generation: replicates numpy double math then float32 cast exactly
// ---------------------------------------------------------------------------
__device__ __forceinline__ float4 anchor_of(int px, int a) {
    const int py = px >> 6, pxx = px & 63;
    const double S[3] = {8.0, 16.0, 32.0};
    const double R[3] = {0.5, 1.0, 2.0};
    const double s = S[a % 3], r = R[a / 3];
    const double h = (16.0 * s) * sqrt(r);
    const double w = (16.0 * s) * sqrt(1.0 / r);
    const float bx1 = (float)(8.0 - w * 0.5);
    const float by1 = (float)(8.0 - h * 0.5);
    const float bx2 = (float)(8.0 + w * 0.5);
    const float by2 = (float)(8.0 + h * 0.5);
    const float sx = (float)(pxx * 16), sy = (float)(py * 16);
    return make_float4(__fadd_rn(sx, bx1), __fadd_rn(sy, by1),
                       __fadd_rn(sx, bx2), __fadd_rn(sy, by2));
}

// ---------------------------------------------------------------------------
// Kernel 1 (v4): 3x3 conv (pad 1) + bias + relu, fp32.
// = R5/R7's v2 kernel with DOUBLE-BUFFERED LDS staging and ONE barrier per
// c-block (was 2). Compute inner loops are character-identical to v2 ->
// conv output is BITWISE IDENTICAL -> downstream selection guaranteed
// (R9/R10 lesson: any new numeric realization is a selection coin-flip;
// only the proven fmaf order is safe).
// grid (16 px-tiles, 16 k-tiles, 8 batch), block 256.
// LDS: sf 2*8*6*72*4 = 27,648 + sw 2*32*8*12*4 = 24,576 -> 52,224 B
// (3 blocks/CU, ~12 waves — about v2's occupancy).
// ---------------------------------------------------------------------------
__global__ __launch_bounds__(256) void conv3x3_k(const float* __restrict__ feat,
                                                 const float* __restrict__ wgt,
                                                 const float* __restrict__ bias,
                                                 float* __restrict__ out) {
    const int b  = blockIdx.z, kt = blockIdx.y, pt = blockIdx.x;
    const int tid = threadIdx.x;
    const int k0 = kt * 32;
    const int y0 = pt * 4;                 // 4 output rows per tile
    __shared__ float sf[2][8][6][72];      // [buf][c][row][col(-1..64)], pad 72
    __shared__ float sw[2][32][8][12];     // [buf][k][c][pos 0..8 (+3 pad)]

    const int kg   = tid >> 5;             // 0..7 -> k = k0+kg*4+i
    const int row  = (tid & 31) >> 3;      // 0..3
    const int col0 = (tid & 7) << 3;       // 0,8,..,56

    float acc[4][8];
#pragma unroll
    for (int i = 0; i < 4; ++i)
#pragma unroll
        for (int p = 0; p < 8; ++p) acc[i][p] = 0.f;

    const float* fb = feat + (size_t)b * (C_ * HW_);

    // ---- stage first c-block into buffer 0 ----
    {
        const int c0 = 0;
        for (int e = tid; e < 8 * 6 * 66; e += 256) {
            int c = e / 396; int rem = e - c * 396;
            int rr = rem / 66; int cc = rem - rr * 66;
            int gy = y0 - 1 + rr, gx = cc - 1;
            float v = 0.f;
            if ((unsigned)gy < 64u && (unsigned)gx < 64u)
                v = fb[(c0 + c) * HW_ + (gy << 6) + gx];
            sf[0][c][rr][cc] = v;
        }
        for (int e = tid; e < 32 * 72; e += 256) {
            int k = e / 72; int rem = e - k * 72;
            int c = rem / 9; int pos = rem - c * 9;
            sw[0][k][c][pos] = wgt[(size_t)(k0 + k) * 4608 + (c0 + c) * 9 + pos];
        }
    }
    __syncthreads();

    for (int c0 = 0; c0 < 512; c0 += 8) {
        const int cur = (c0 >> 3) & 1, nxt = cur ^ 1;
        // ---- stage NEXT c-block into the other buffer (no barrier before
        //      compute: writes go to nxt, reads come from cur) ----
        if (c0 + 8 < 512) {
            const int c0n = c0 + 8;
            for (int e = tid; e < 8 * 6 * 66; e += 256) {
                int c = e / 396; int rem = e - c * 396;
                int rr = rem / 66; int cc = rem - rr * 66;
                int gy = y0 - 1 + rr, gx = cc - 1;
                float v = 0.f;
                if ((unsigned)gy < 64u && (unsigned)gx < 64u)
                    v = fb[(c0n + c) * HW_ + (gy << 6) + gx];
                sf[nxt][c][rr][cc] = v;
            }
            for (int e = tid; e < 32 * 72; e += 256) {
                int k = e / 72; int rem = e - k * 72;
                int c = rem / 9; int pos = rem - c * 9;
                sw[nxt][k][c][pos] = wgt[(size_t)(k0 + k) * 4608 + (c0n + c) * 9 + pos];
            }
        }

        // ---- compute from cur buffer (identical to v2's inner loops) ----
#pragma unroll
        for (int c = 0; c < 8; ++c) {
            float fr[3][10];
#pragma unroll
            for (int dy = 0; dy < 3; ++dy) {
                const float* rp = &sf[cur][c][row + dy][col0];
                float4 aa = *(const float4*)rp;
                float4 bb = *(const float4*)(rp + 4);
                float2 c2 = *(const float2*)(rp + 8);
                fr[dy][0]=aa.x; fr[dy][1]=aa.y; fr[dy][2]=aa.z; fr[dy][3]=aa.w;
                fr[dy][4]=bb.x; fr[dy][5]=bb.y; fr[dy][6]=bb.z; fr[dy][7]=bb.w;
                fr[dy][8]=c2.x; fr[dy][9]=c2.y;
            }
#pragma unroll
            for (int i = 0; i < 4; ++i) {
                const float* wp = &sw[cur][kg * 4 + i][c][0];
                const float4 wA = *(const float4*)wp;
                const float4 wB = *(const float4*)(wp + 4);
                const float  w8 = wp[8];
                const float wv[9] = {wA.x, wA.y, wA.z, wA.w, wB.x, wB.y, wB.z, wB.w, w8};
#pragma unroll
                for (int dy = 0; dy < 3; ++dy)
#pragma unroll
                    for (int dx = 0; dx < 3; ++dx) {
                        const float wq = wv[dy * 3 + dx];
#pragma unroll
                        for (int p = 0; p < 8; ++p)
                            acc[i][p] = fmaf(fr[dy][p + dx], wq, acc[i][p]);
                    }
            }
        }
        // one barrier: (a) nxt fully written before next iter reads it;
        // (b) cur fully read before next-next staging overwrites it.
        __syncthreads();
    }
    // epilogue: +bias, relu, store (identical to v2)
#pragma unroll
    for (int i = 0; i < 4; ++i) {
        const int k = k0 + kg * 4 + i;
        const float bs = bias[k];
        float4 v0, v1;
        v0.x = fmaxf(__fadd_rn(acc[i][0], bs), 0.f);
        v0.y = fmaxf(__fadd_rn(acc[i][1], bs), 0.f);
        v0.z = fmaxf(__fadd_rn(acc[i][2], bs), 0.f);
        v0.w = fmaxf(__fadd_rn(acc[i][3], bs), 0.f);
        v1.x = fmaxf(__fadd_rn(acc[i][4], bs), 0.f);
        v1.y = fmaxf(__fadd_rn(acc[i][5], bs), 0.f);
        v1.z = fmaxf(__fadd_rn(acc[i][6], bs), 0.f);
        v1.w = fmaxf(__fadd_rn(acc[i][7], bs), 0.f);
        float* op = out + ((size_t)b * C_ + k) * HW_ + ((y0 + row) << 6) + col0;
        *(float4*)op = v0;
        *(float4*)(op + 4) = v1;
    }
}

// ---------------------------------------------------------------------------
// Kernel 1b: transpose 1x1 head weights into [c][o]. o>=54 ZERO (R5 fix).
// ---------------------------------------------------------------------------
__global__ __launch_bounds__(256) void wprep_k(const float* __restrict__ loc_w,
                                               const float* __restrict__ cls_w,
                                               float* __restrict__ wt) {
    int idx = blockIdx.x * 256 + threadIdx.x;          // 112 blocks * 256 = 28672
    int c = idx / 56, o = idx - c * 56;
    float v = (o < 36) ? loc_w[o * 512 + c]
            : (o < 54) ? cls_w[(o - 36) * 512 + c]
            : 0.0f;                                    // pad
    wt[idx] = v;
}

// ---------------------------------------------------------------------------
// Kernel 2: 1x1 heads. Unchanged from R5 (validated).
// ---------------------------------------------------------------------------
__global__ __launch_bounds__(256) void head_k(const float* __restrict__ conv,
                                              const float* __restrict__ wt,
                                              const float* __restrict__ loc_b,
                                              const float* __restrict__ cls_b,
                                              float* __restrict__ out) {
    const int blk = blockIdx.x;
    const int b = blk >> 6, px0 = (blk & 63) << 6;
    const int tid = threadIdx.x;
    const int og = tid >> 6, pxl = tid & 63;
    __shared__ float sW[64][64];   // [c][slot], slot = og*16 + q
    __shared__ float sF[64][72];   // [c][px], pad 72

    float acc[14];
#pragma unroll
    for (int q = 0; q < 14; ++q) acc[q] = 0.f;

    for (int cc0 = 0; cc0 < 512; cc0 += 64) {
        __syncthreads();
        for (int e = tid; e < 64 * 56; e += 256) {
            int c = e / 56, o = e - c * 56;
            int slot = (o >= 42) ? o + 6 : (o >= 28) ? o + 4 : (o >= 14) ? o + 2 : o;
            sW[c][slot] = wt[(cc0 + c) * 56 + o];
        }
        for (int e = tid; e < 1024; e += 256) {
            int c = e >> 4, p4 = (e & 15) << 2;
            *(float4*)&sF[c][p4] =
                *(const float4*)&conv[((size_t)b * C_ + cc0 + c) * HW_ + px0 + p4];
        }
        __syncthreads();
#pragma unroll 4
        for (int c = 0; c < 64; ++c) {
            const float a = sF[c][pxl];
            const float* wp = &sW[c][og * 16];
            float4 w0 = *(const float4*)wp;
            float4 w1 = *(const float4*)(wp + 4);
            float4 w2 = *(const float4*)(wp + 8);
            float2 w3 = *(const float2*)(wp + 12);
            acc[0]  = fmaf(a, w0.x, acc[0]);   acc[1]  = fmaf(a, w0.y, acc[1]);
            acc[2]  = fmaf(a, w0.z, acc[2]);   acc[3]  = fmaf(a, w0.w, acc[3]);
            acc[4]  = fmaf(a, w1.x, acc[4]);   acc[5]  = fmaf(a, w1.y, acc[5]);
            acc[6]  = fmaf(a, w1.z, acc[6]);   acc[7]  = fmaf(a, w1.w, acc[7]);
            acc[8]  = fmaf(a, w2.x, acc[8]);   acc[9]  = fmaf(a, w2.y, acc[9]);
            acc[10] = fmaf(a, w2.z, acc[10]);  acc[11] = fmaf(a, w2.w, acc[11]);
            acc[12] = fmaf(a, w3.x, acc[12]);  acc[13] = fmaf(a, w3.y, acc[13]);
        }
    }
    const int px = px0 + pxl;
    const size_t nb = (size_t)b * NA + (size_t)px * 9;
#pragma unroll
    for (int q = 0; q < 14; ++q) {
        int o = og * 14 + q;
        if (o >= 54) continue;               // pad outputs: DO NOT STORE
        float bsv = (o < 36) ? loc_b[o] : cls_b[o - 36];
        float v = __fadd_rn(acc[q], bsv);
        if (o < 36) out[LOC_OFF + nb * 4 + o] = v;
        else        out[SC_OFF + nb * 2 + (o - 36)] = v;
    }
}

// ---------------------------------------------------------------------------
// Kernel 3: per-anchor decode. Unchanged from R5 (validated).
// ---------------------------------------------------------------------------
__global__ __launch_bounds__(256) void decode_k(const int* __restrict__ ih,
                                                const int* __restrict__ iw,
                                                float* __restrict__ out,
                                                float* __restrict__ boxes,
                                                u64* __restrict__ keys) {
    const int b = blockIdx.x;
    const int n = blockIdx.y * 256 + threadIdx.x;
    const float4 lv = *(const float4*)(out + LOC_OFF + ((size_t)b * NA + n) * 4);
    const float2 sc = *(const float2*)(out + SC_OFF + ((size_t)b * NA + n) * 2);
    const int px = n / 9, a = n - 9 * px;
    const float4 an = anchor_of(px, a);

    const float fw = (float)iw[0], fh = (float)ih[0];
    const float s0 = sc.x, s1 = sc.y;
    const float m  = fmaxf(s0, s1);
    const float e0 = (float)exp((double)__fsub_rn(s0, m));
    const float e1 = (float)exp((double)__fsub_rn(s1, m));
    const float fg = __fdiv_rn(e1, __fadd_rn(e0, e1));

    const float wa  = __fsub_rn(an.z, an.x), ha = __fsub_rn(an.w, an.y);
    const float cxa = __fadd_rn(an.x, __fmul_rn(0.5f, wa));
    const float cya = __fadd_rn(an.y, __fmul_rn(0.5f, ha));
    const float cx = __fadd_rn(__fmul_rn(lv.x, wa), cxa);
    const float cy = __fadd_rn(__fmul_rn(lv.y, ha), cya);
    const float ww = __fmul_rn((float)exp((double)lv.z), wa);
    const float hh = __fmul_rn((float)exp((double)lv.w), ha);
    float x1 = __fsub_rn(cx, __fmul_rn(0.5f, ww));
    float y1 = __fsub_rn(cy, __fmul_rn(0.5f, hh));
    float x2 = __fadd_rn(cx, __fmul_rn(0.5f, ww));
    float y2 = __fadd_rn(cy, __fmul_rn(0.5f, hh));
    x1 = fminf(fmaxf(x1, 0.f), fw);  y1 = fminf(fmaxf(y1, 0.f), fh);
    x2 = fminf(fmaxf(x2, 0.f), fw);  y2 = fminf(fmaxf(y2, 0.f), fh);

    *(float4*)(boxes + ((size_t)b * NA + n) * 4) = make_float4(x1, y1, x2, y2);

    const float ws_ = __fsub_rn(x2, x1), hs_ = __fsub_rn(y2, y1);
    const bool valid = (ws_ >= 16.f) && (hs_ >= 16.f);
    const u32 bits = __float_as_uint(fg);
    const u32 key32 = valid ? (bits | 0x80000000u) : 0x007FFFFFu;
    keys[(size_t)b * NA + n] = ((u64)key32 << 16) | (u64)(65535 - n);

    if (b == 0)
        *(float4*)(out + ANCH_OFF + (size_t)n * 4) = an;
}

// ---------------------------------------------------------------------------
// Kernel 4: per-image exact top-2000 (radix select, unique 48-bit keys),
// bitonic sort, write sorted boxes + valid bitmask. grid (8), block 256.
// ---------------------------------------------------------------------------
__global__ __launch_bounds__(256) void select_k(const u64* __restrict__ keys_g,
                                                const float* __restrict__ boxes_g,
                                                float4* __restrict__ sorted,
                                                u32* __restrict__ validw) {
    const int b = blockIdx.x;
    const u64* keys = keys_g + (size_t)b * NA;
    const float4* boxes = ((const float4*)boxes_g) + (size_t)b * NA;
    const int tid = threadIdx.x;

    __shared__ u64 skey[2048];
    __shared__ float4 sbox[2048];
    __shared__ u32 hist[256];
    __shared__ int scal[4];
    __shared__ unsigned char kb[2048];

    // ---- radix select: exact 2000th-largest 48-bit key ----
    u64 prefix = 0; int rem = PRE_NMS;
    for (int shift = 40; shift >= 0; shift -= 8) {
        hist[tid] = 0;
        __syncthreads();
        const u64 ph = prefix >> (shift + 8);
        for (int e = tid; e < NA; e += 256) {
            u64 k = keys[e];
            if ((k >> (shift + 8)) == ph)
                atomicAdd(&hist[(u32)(k >> shift) & 255u], 1u);
        }
        __syncthreads();
        if (tid == 0) {
            int cum = 0, dsel = 0;
            for (int d = 255; d >= 0; --d) {
                int c = (int)hist[d];
                if (cum + c >= rem) { dsel = d; break; }
                cum += c;
            }
            scal[0] = dsel; scal[1] = cum;
        }
        __syncthreads();
        prefix |= ((u64)(u32)scal[0]) << shift;
        rem -= scal[1];
        __syncthreads();
    }
    const u64 kstar = prefix;

    // ---- collect the 2000 keys >= kstar ----
    if (tid == 0) scal[2] = 0;
    __syncthreads();
    for (int e = tid; e < NA; e += 256) {
        u64 k = keys[e];
        if (k >= kstar) { int p = atomicAdd(&scal[2], 1); if (p < 2048) skey[p] = k; }
    }
    __syncthreads();
    for (int r = scal[2] + tid; r < 2048; r += 256) skey[r] = 0;
    __syncthreads();

    // ---- bitonic sort 2048 u64 descending ----
    for (int kk = 2; kk <= 2048; kk <<= 1) {
        for (int j = kk >> 1; j > 0; j >>= 1) {
            for (int i = tid; i < 2048; i += 256) {
                int l = i ^ j;
                if (l > i) {
                    u64 a = skey[i], c = skey[l];
                    bool desc = ((i & kk) == 0);
                    if (desc ? (a < c) : (a > c)) { skey[i] = c; skey[l] = a; }
                }
            }
            __syncthreads();
        }
    }

    // ---- gather boxes + validity; write out ----
    for (int r = tid; r < 2048; r += 256) {
        if (r < PRE_NMS) {
            u64 k = skey[r];
            int idx = 65535 - (int)(k & 0xFFFFu);
            if (idx >= NA) idx = NA - 1;
            sbox[r] = boxes[idx];
            kb[r] = ((u32)(k >> 16) > 0x007FFFFFu) ? 1 : 0;
        } else { sbox[r] = make_float4(0, 0, 0, 0); kb[r] = 0; }
    }
    __syncthreads();
    for (int r = tid; r < 2048; r += 256)
        sorted[(size_t)b * 2048 + r] = sbox[r];
    if (tid < 64) {
        u32 v = 0;
#pragma unroll
        for (int bit = 0; bit < 32; ++bit)
            v |= ((u32)kb[tid * 32 + bit]) << bit;
        validw[b * 64 + tid] = v;
    }
}

// ---------------------------------------------------------------------------
// Kernel 5: all-pairs IoU suppression bitmask. grid (8, 16), block 256.
// ---------------------------------------------------------------------------
__global__ __launch_bounds__(256) void mask_k(const float4* __restrict__ sorted,
                                              u32* __restrict__ rows) {
    const int b = blockIdx.x, chunk = blockIdx.y;
    const int tid = threadIdx.x;
    __shared__ float4 sbx[2048];
    __shared__ float  sar[2048];
    const float4* src = sorted + (size_t)b * 2048;
    for (int e = tid; e < 2048; e += 256) {
        float4 v = src[e];
        sbx[e] = v;
        sar[e] = __fmul_rn(__fsub_rn(v.z, v.x), __fsub_rn(v.w, v.y));
    }
    __syncthreads();
    const int i = chunk * 128 + (tid & 127);
    const int half = tid >> 7;
    const float4 bi = sbx[i];
    const float  ai = sar[i];
    u32* rp = rows + ((size_t)b * 2048 + i) * 64;
    for (int jw = half * 32; jw < half * 32 + 32; ++jw) {
        u32 bits = 0;
#pragma unroll
        for (int jb = 0; jb < 32; ++jb) {
            int j = jw * 32 + jb;
            float4 bj = sbx[j];
            float lx = fmaxf(bi.x, bj.x), ly = fmaxf(bi.y, bj.y);
            float rx = fminf(bi.z, bj.z), ry = fminf(bi.w, bj.w);
            float wv = fmaxf(__fsub_rn(rx, lx), 0.f);
            float hv = fmaxf(__fsub_rn(ry, ly), 0.f);
            float inter = __fmul_rn(wv, hv);
            float den = __fadd_rn(__fsub_rn(__fadd_rn(ai, sar[j]), inter), 1e-9f);
            float iou = __fdiv_rn(inter, den);
            if (iou > 0.7f) bits |= (1u << jb);
        }
        rp[jw] = bits;
    }
}

// ---------------------------------------------------------------------------
// Kernel 6: greedy bit-sweep (one wave per image, prefetched rows), then
// parallel rank/compact. grid (8), block 64.
// ---------------------------------------------------------------------------
__global__ __launch_bounds__(64) void sweep_k(const u32* __restrict__ rows,
                                              const u32* __restrict__ validw,
                                              const float4* __restrict__ sorted,
                                              float* __restrict__ out) {
    const int b = blockIdx.x;
    const int lane = threadIdx.x;
    const u32* R = rows + (size_t)b * 2048 * 64;
    u32 vbits = validw[b * 64 + lane];
    u32 acc = 0, kw = 0;
    u32 pf[8];
#pragma unroll
    for (int s = 0; s < 8; ++s) pf[s] = R[(size_t)s * 64 + lane];
    for (int ib = 0; ib < PRE_NMS; ib += 8) {
#pragma unroll
        for (int s = 0; s < 8; ++s) {
            const int i = ib + s;
            u32 aw = (u32)__shfl((int)acc,   i >> 5, 64);
            u32 vw = (u32)__shfl((int)vbits, i >> 5, 64);
            bool live = ((vw >> (i & 31)) & 1u) && !((aw >> (i & 31)) & 1u);
            if (live) {
                acc |= pf[s];
                if (lane == (i >> 5)) kw |= 1u << (i & 31);
            }
            pf[s] = R[(size_t)(i + 8) * 64 + lane];   // i+8 <= 2007 < 2048
        }
    }
    __shared__ u32 kws[64];
    __shared__ int pfx[65];
    kws[lane] = kw;
    __syncthreads();
    if (lane == 0) {
        int s = 0;
        for (int w = 0; w < 64; ++w) { pfx[w] = s; s += __popc(kws[w]); }
        pfx[64] = s;
    }
    __syncthreads();
    float* rois = out + ROIS_OFF + (size_t)b * POST_NMS * 4;
    const float4* src = sorted + (size_t)b * 2048;
    for (int i2 = lane; i2 < 2048; i2 += 64) {
        int w = i2 >> 5; u32 word = kws[w];
        if ((word >> (i2 & 31)) & 1u) {
            int rank = pfx[w] + __popc(word & ((1u << (i2 & 31)) - 1u));
            if (rank < POST_NMS) {
                float4 v = src[i2];
                *(float4*)(rois + rank * 4) = v;
            }
        }
    }
    int kc = pfx[64]; if (kc > POST_NMS) kc = POST_NMS;
    for (int j = kc + lane; j < POST_NMS; j += 64)
        *(float4*)(rois + j * 4) = make_float4(0, 0, 0, 0);
    float* rip = out + IDX_OFF + (size_t)b * POST_NMS;
    for (int j = lane; j < POST_NMS; j += 64) rip[j] = (float)b;
}

// ---------------------------------------------------------------------------
extern "C" void kernel_launch(void* const* d_in, const int* in_sizes, int n_in,
                              void* d_out, int out_size, void* d_ws, size_t ws_size,
                              hipStream_t stream) {
    const float* feat    = (const float*)d_in[0];
    const float* conv1_w = (const float*)d_in[1];
    const float* conv1_b = (const float*)d_in[2];
    const float* cls_w   = (const float*)d_in[3];
    const float* cls_b   = (const float*)d_in[4];
    const float* loc_w   = (const float*)d_in[5];
    const float* loc_b   = (const float*)d_in[6];
    const int*   ih      = (const int*)d_in[7];
    const int*   iw      = (const int*)d_in[8];
    float* out = (float*)d_out;

    // ws layout: R8's proven 71.2 MB envelope.
    //   conv_ws  : 8*512*4096 f32 = 67,108,864 B  (front 4.5 MB re-aliased by
    //              rows/sorted/valid AFTER head_k — stream-ordered safe)
    //   boxes_ws : 8*36864*4 f32  =  4,718,592 B
    //   keys_ws  : 8*36864 u64    =  2,359,296 B
    //   wt_ws    : 512*56 f32     =    114,688 B
    float* conv_ws  = (float*)d_ws;
    float* boxes_ws = conv_ws + (size_t)B_ * C_ * HW_;
    u64*   keys_ws  = (u64*)(boxes_ws + (size_t)B_ * NA * 4);
    float* wt_ws    = (float*)(keys_ws + (size_t)B_ * NA);
    u32*    rows_ws   = (u32*)d_ws;                                      // alias
    float4* sorted_ws = (float4*)((char*)d_ws + (4u << 20));             // alias
    u32*    valid_ws  = (u32*)((char*)d_ws + (4u << 20) + (512u << 10)); // alias

    hipLaunchKernelGGL(wprep_k, dim3(112), dim3(256), 0, stream, loc_w, cls_w, wt_ws);
    hipLaunchKernelGGL(conv3x3_k, dim3(16, 16, 8), dim3(256), 0, stream,
                       feat, conv1_w, conv1_b, conv_ws);
    hipLaunchKernelGGL(head_k, dim3(512), dim3(256), 0, stream,
                       conv_ws, wt_ws, loc_b, cls_b, out);
    hipLaunchKernelGGL(decode_k, dim3(8, 144), dim3(256), 0, stream,
                       ih, iw, out, boxes_ws, keys_ws);
    hipLaunchKernelGGL(select_k, dim3(8), dim3(256), 0, stream,
                       keys_ws, boxes_ws, sorted_ws, valid_ws);
    hipLaunchKernelGGL(mask_k, dim3(8, 16), dim3(256), 0, stream,
                       sorted_ws, rows_ws);
    hipLaunchKernelGGL(sweep_k, dim3(8), dim3(64), 0, stream,
                       rows_ws, valid_ws, sorted_ws, out);
}

// Round 12
// 2931.042 us; speedup vs baseline: 1.0793x; 1.0793x over previous
//
#include <hip/hip_runtime.h>
#include <math.h>

typedef unsigned int u32;
typedef unsigned long long u64;

#define B_    8
#define C_    512
#define HW_   4096
#define NA    36864        // 4096*9 anchors per image
#define PRE_NMS  2000
#define POST_NMS 300

// output flat offsets (floats)
#define LOC_OFF   0
#define SC_OFF    1179648
#define ROIS_OFF  1769472
#define IDX_OFF   1779072
#define ANCH_OFF  1781472

// ---------------------------------------------------------------------------
// anchor generation: replicates numpy double math then float32 cast exactly
// ---------------------------------------------------------------------------
__device__ __forceinline__ float4 anchor_of(int px, int a) {
    const int py = px >> 6, pxx = px & 63;
    const double S[3] = {8.0, 16.0, 32.0};
    const double R[3] = {0.5, 1.0, 2.0};
    const double s = S[a % 3], r = R[a / 3];
    const double h = (16.0 * s) * sqrt(r);
    const double w = (16.0 * s) * sqrt(1.0 / r);
    const float bx1 = (float)(8.0 - w * 0.5);
    const float by1 = (float)(8.0 - h * 0.5);
    const float bx2 = (float)(8.0 + w * 0.5);
    const float by2 = (float)(8.0 + h * 0.5);
    const float sx = (float)(pxx * 16), sy = (float)(py * 16);
    return make_float4(__fadd_rn(sx, bx1), __fadd_rn(sy, by1),
                       __fadd_rn(sx, bx2), __fadd_rn(sy, by2));
}

// ---------------------------------------------------------------------------
// Kernel 1: 3x3 conv — R5/R7 v2 kernel VERBATIM (2770 us, session best).
// Variant ledger: v2=2770 < v3(dy-outer)=3000 < v4(dbuf,pad72)=3170 <
// 16k-scalar=4285. MFMA realizations flip NMS selection (R9/R10) — only
// this exact fmaf order is proven selection-safe. DO NOT MODIFY.
// ---------------------------------------------------------------------------
__global__ __launch_bounds__(256) void conv3x3_k(const float* __restrict__ feat,
                                                 const float* __restrict__ wgt,
                                                 const float* __restrict__ bias,
                                                 float* __restrict__ out) {
    const int b  = blockIdx.z, kt = blockIdx.y, pt = blockIdx.x;
    const int tid = threadIdx.x;
    const int k0 = kt * 32;
    const int y0 = pt * 4;                 // 4 output rows per tile
    __shared__ float sf[8][6][76];         // [c][row][col(-1..64)], pad 76
    __shared__ float sw[32][8][12];        // [k][c][pos 0..8 (+3 pad)]

    const int kg   = tid >> 5;             // 0..7 -> k = k0+kg*4+i
    const int row  = (tid & 31) >> 3;      // 0..3
    const int col0 = (tid & 7) << 3;       // 0,8,..,56

    float acc[4][8];
#pragma unroll
    for (int i = 0; i < 4; ++i)
#pragma unroll
        for (int p = 0; p < 8; ++p) acc[i][p] = 0.f;

    const float* fb = feat + (size_t)b * (C_ * HW_);

    for (int c0 = 0; c0 < 512; c0 += 8) {
        __syncthreads();
        // stage feature tile: 8c x 6 rows x 66 cols (zero-padded halo)
        for (int e = tid; e < 8 * 6 * 66; e += 256) {
            int c = e / 396; int rem = e - c * 396;
            int rr = rem / 66; int cc = rem - rr * 66;
            int gy = y0 - 1 + rr, gx = cc - 1;
            float v = 0.f;
            if ((unsigned)gy < 64u && (unsigned)gx < 64u)
                v = fb[(c0 + c) * HW_ + (gy << 6) + gx];
            sf[c][rr][cc] = v;
        }
        // stage weights: 32k x 8c x 9
        for (int e = tid; e < 32 * 72; e += 256) {
            int k = e / 72; int rem = e - k * 72;
            int c = rem / 9; int pos = rem - c * 9;
            sw[k][c][pos] = wgt[(size_t)(k0 + k) * 4608 + (c0 + c) * 9 + pos];
        }
        __syncthreads();

#pragma unroll
        for (int c = 0; c < 8; ++c) {
            float fr[3][10];
#pragma unroll
            for (int dy = 0; dy < 3; ++dy) {
                const float* rp = &sf[c][row + dy][col0];
                float4 aa = *(const float4*)rp;
                float4 bb = *(const float4*)(rp + 4);
                float2 c2 = *(const float2*)(rp + 8);
                fr[dy][0]=aa.x; fr[dy][1]=aa.y; fr[dy][2]=aa.z; fr[dy][3]=aa.w;
                fr[dy][4]=bb.x; fr[dy][5]=bb.y; fr[dy][6]=bb.z; fr[dy][7]=bb.w;
                fr[dy][8]=c2.x; fr[dy][9]=c2.y;
            }
#pragma unroll
            for (int i = 0; i < 4; ++i) {
                const float* wp = &sw[kg * 4 + i][c][0];
                const float4 wA = *(const float4*)wp;
                const float4 wB = *(const float4*)(wp + 4);
                const float  w8 = wp[8];
                const float wv[9] = {wA.x, wA.y, wA.z, wA.w, wB.x, wB.y, wB.z, wB.w, w8};
#pragma unroll
                for (int dy = 0; dy < 3; ++dy)
#pragma unroll
                    for (int dx = 0; dx < 3; ++dx) {
                        const float wq = wv[dy * 3 + dx];
#pragma unroll
                        for (int p = 0; p < 8; ++p)
                            acc[i][p] = fmaf(fr[dy][p + dx], wq, acc[i][p]);
                    }
            }
        }
    }
    // epilogue: +bias, relu, store
#pragma unroll
    for (int i = 0; i < 4; ++i) {
        const int k = k0 + kg * 4 + i;
        const float bs = bias[k];
        float4 v0, v1;
        v0.x = fmaxf(__fadd_rn(acc[i][0], bs), 0.f);
        v0.y = fmaxf(__fadd_rn(acc[i][1], bs), 0.f);
        v0.z = fmaxf(__fadd_rn(acc[i][2], bs), 0.f);
        v0.w = fmaxf(__fadd_rn(acc[i][3], bs), 0.f);
        v1.x = fmaxf(__fadd_rn(acc[i][4], bs), 0.f);
        v1.y = fmaxf(__fadd_rn(acc[i][5], bs), 0.f);
        v1.z = fmaxf(__fadd_rn(acc[i][6], bs), 0.f);
        v1.w = fmaxf(__fadd_rn(acc[i][7], bs), 0.f);
        float* op = out + ((size_t)b * C_ + k) * HW_ + ((y0 + row) << 6) + col0;
        *(float4*)op = v0;
        *(float4*)(op + 4) = v1;
    }
}

// ---------------------------------------------------------------------------
// Kernel 1b: transpose 1x1 head weights into [c][o]. o>=54 ZERO (R5 fix).
// ---------------------------------------------------------------------------
__global__ __launch_bounds__(256) void wprep_k(const float* __restrict__ loc_w,
                                               const float* __restrict__ cls_w,
                                               float* __restrict__ wt) {
    int idx = blockIdx.x * 256 + threadIdx.x;          // 112 blocks * 256 = 28672
    int c = idx / 56, o = idx - c * 56;
    float v = (o < 36) ? loc_w[o * 512 + c]
            : (o < 54) ? cls_w[(o - 36) * 512 + c]
            : 0.0f;                                    // pad
    wt[idx] = v;
}

// ---------------------------------------------------------------------------
// Kernel 2: 1x1 heads. Unchanged from R5 (validated).
// ---------------------------------------------------------------------------
__global__ __launch_bounds__(256) void head_k(const float* __restrict__ conv,
                                              const float* __restrict__ wt,
                                              const float* __restrict__ loc_b,
                                              const float* __restrict__ cls_b,
                                              float* __restrict__ out) {
    const int blk = blockIdx.x;
    const int b = blk >> 6, px0 = (blk & 63) << 6;
    const int tid = threadIdx.x;
    const int og = tid >> 6, pxl = tid & 63;
    __shared__ float sW[64][64];   // [c][slot], slot = og*16 + q
    __shared__ float sF[64][72];   // [c][px], pad 72

    float acc[14];
#pragma unroll
    for (int q = 0; q < 14; ++q) acc[q] = 0.f;

    for (int cc0 = 0; cc0 < 512; cc0 += 64) {
        __syncthreads();
        for (int e = tid; e < 64 * 56; e += 256) {
            int c = e / 56, o = e - c * 56;
            int slot = (o >= 42) ? o + 6 : (o >= 28) ? o + 4 : (o >= 14) ? o + 2 : o;
            sW[c][slot] = wt[(cc0 + c) * 56 + o];
        }
        for (int e = tid; e < 1024; e += 256) {
            int c = e >> 4, p4 = (e & 15) << 2;
            *(float4*)&sF[c][p4] =
                *(const float4*)&conv[((size_t)b * C_ + cc0 + c) * HW_ + px0 + p4];
        }
        __syncthreads();
#pragma unroll 4
        for (int c = 0; c < 64; ++c) {
            const float a = sF[c][pxl];
            const float* wp = &sW[c][og * 16];
            float4 w0 = *(const float4*)wp;
            float4 w1 = *(const float4*)(wp + 4);
            float4 w2 = *(const float4*)(wp + 8);
            float2 w3 = *(const float2*)(wp + 12);
            acc[0]  = fmaf(a, w0.x, acc[0]);   acc[1]  = fmaf(a, w0.y, acc[1]);
            acc[2]  = fmaf(a, w0.z, acc[2]);   acc[3]  = fmaf(a, w0.w, acc[3]);
            acc[4]  = fmaf(a, w1.x, acc[4]);   acc[5]  = fmaf(a, w1.y, acc[5]);
            acc[6]  = fmaf(a, w1.z, acc[6]);   acc[7]  = fmaf(a, w1.w, acc[7]);
            acc[8]  = fmaf(a, w2.x, acc[8]);   acc[9]  = fmaf(a, w2.y, acc[9]);
            acc[10] = fmaf(a, w2.z, acc[10]);  acc[11] = fmaf(a, w2.w, acc[11]);
            acc[12] = fmaf(a, w3.x, acc[12]);  acc[13] = fmaf(a, w3.y, acc[13]);
        }
    }
    const int px = px0 + pxl;
    const size_t nb = (size_t)b * NA + (size_t)px * 9;
#pragma unroll
    for (int q = 0; q < 14; ++q) {
        int o = og * 14 + q;
        if (o >= 54) continue;               // pad outputs: DO NOT STORE
        float bsv = (o < 36) ? loc_b[o] : cls_b[o - 36];
        float v = __fadd_rn(acc[q], bsv);
        if (o < 36) out[LOC_OFF + nb * 4 + o] = v;
        else        out[SC_OFF + nb * 2 + (o - 36)] = v;
    }
}

// ---------------------------------------------------------------------------
// Kernel 3: per-anchor decode. Unchanged from R5 (validated).
// ---------------------------------------------------------------------------
__global__ __launch_bounds__(256) void decode_k(const int* __restrict__ ih,
                                                const int* __restrict__ iw,
                                                float* __restrict__ out,
                                                float* __restrict__ boxes,
                                                u64* __restrict__ keys) {
    const int b = blockIdx.x;
    const int n = blockIdx.y * 256 + threadIdx.x;
    const float4 lv = *(const float4*)(out + LOC_OFF + ((size_t)b * NA + n) * 4);
    const float2 sc = *(const float2*)(out + SC_OFF + ((size_t)b * NA + n) * 2);
    const int px = n / 9, a = n - 9 * px;
    const float4 an = anchor_of(px, a);

    const float fw = (float)iw[0], fh = (float)ih[0];
    const float s0 = sc.x, s1 = sc.y;
    const float m  = fmaxf(s0, s1);
    const float e0 = (float)exp((double)__fsub_rn(s0, m));
    const float e1 = (float)exp((double)__fsub_rn(s1, m));
    const float fg = __fdiv_rn(e1, __fadd_rn(e0, e1));

    const float wa  = __fsub_rn(an.z, an.x), ha = __fsub_rn(an.w, an.y);
    const float cxa = __fadd_rn(an.x, __fmul_rn(0.5f, wa));
    const float cya = __fadd_rn(an.y, __fmul_rn(0.5f, ha));
    const float cx = __fadd_rn(__fmul_rn(lv.x, wa), cxa);
    const float cy = __fadd_rn(__fmul_rn(lv.y, ha), cya);
    const float ww = __fmul_rn((float)exp((double)lv.z), wa);
    const float hh = __fmul_rn((float)exp((double)lv.w), ha);
    float x1 = __fsub_rn(cx, __fmul_rn(0.5f, ww));
    float y1 = __fsub_rn(cy, __fmul_rn(0.5f, hh));
    float x2 = __fadd_rn(cx, __fmul_rn(0.5f, ww));
    float y2 = __fadd_rn(cy, __fmul_rn(0.5f, hh));
    x1 = fminf(fmaxf(x1, 0.f), fw);  y1 = fminf(fmaxf(y1, 0.f), fh);
    x2 = fminf(fmaxf(x2, 0.f), fw);  y2 = fminf(fmaxf(y2, 0.f), fh);

    *(float4*)(boxes + ((size_t)b * NA + n) * 4) = make_float4(x1, y1, x2, y2);

    const float ws_ = __fsub_rn(x2, x1), hs_ = __fsub_rn(y2, y1);
    const bool valid = (ws_ >= 16.f) && (hs_ >= 16.f);
    const u32 bits = __float_as_uint(fg);
    const u32 key32 = valid ? (bits | 0x80000000u) : 0x007FFFFFu;
    keys[(size_t)b * NA + n] = ((u64)key32 << 16) | (u64)(65535 - n);

    if (b == 0)
        *(float4*)(out + ANCH_OFF + (size_t)n * 4) = an;
}

// ---------------------------------------------------------------------------
// Kernel 4: per-image exact top-2000 (radix select, unique 48-bit keys),
// bitonic sort, write sorted boxes + valid bitmask. grid (8), block 256.
// ---------------------------------------------------------------------------
__global__ __launch_bounds__(256) void select_k(const u64* __restrict__ keys_g,
                                                const float* __restrict__ boxes_g,
                                                float4* __restrict__ sorted,
                                                u32* __restrict__ validw) {
    const int b = blockIdx.x;
    const u64* keys = keys_g + (size_t)b * NA;
    const float4* boxes = ((const float4*)boxes_g) + (size_t)b * NA;
    const int tid = threadIdx.x;

    __shared__ u64 skey[2048];
    __shared__ float4 sbox[2048];
    __shared__ u32 hist[256];
    __shared__ int scal[4];
    __shared__ unsigned char kb[2048];

    // ---- radix select: exact 2000th-largest 48-bit key ----
    u64 prefix = 0; int rem = PRE_NMS;
    for (int shift = 40; shift >= 0; shift -= 8) {
        hist[tid] = 0;
        __syncthreads();
        const u64 ph = prefix >> (shift + 8);
        for (int e = tid; e < NA; e += 256) {
            u64 k = keys[e];
            if ((k >> (shift + 8)) == ph)
                atomicAdd(&hist[(u32)(k >> shift) & 255u], 1u);
        }
        __syncthreads();
        if (tid == 0) {
            int cum = 0, dsel = 0;
            for (int d = 255; d >= 0; --d) {
                int c = (int)hist[d];
                if (cum + c >= rem) { dsel = d; break; }
                cum += c;
            }
            scal[0] = dsel; scal[1] = cum;
        }
        __syncthreads();
        prefix |= ((u64)(u32)scal[0]) << shift;
        rem -= scal[1];
        __syncthreads();
    }
    const u64 kstar = prefix;

    // ---- collect the 2000 keys >= kstar ----
    if (tid == 0) scal[2] = 0;
    __syncthreads();
    for (int e = tid; e < NA; e += 256) {
        u64 k = keys[e];
        if (k >= kstar) { int p = atomicAdd(&scal[2], 1); if (p < 2048) skey[p] = k; }
    }
    __syncthreads();
    for (int r = scal[2] + tid; r < 2048; r += 256) skey[r] = 0;
    __syncthreads();

    // ---- bitonic sort 2048 u64 descending ----
    for (int kk = 2; kk <= 2048; kk <<= 1) {
        for (int j = kk >> 1; j > 0; j >>= 1) {
            for (int i = tid; i < 2048; i += 256) {
                int l = i ^ j;
                if (l > i) {
                    u64 a = skey[i], c = skey[l];
                    bool desc = ((i & kk) == 0);
                    if (desc ? (a < c) : (a > c)) { skey[i] = c; skey[l] = a; }
                }
            }
            __syncthreads();
        }
    }

    // ---- gather boxes + validity; write out ----
    for (int r = tid; r < 2048; r += 256) {
        if (r < PRE_NMS) {
            u64 k = skey[r];
            int idx = 65535 - (int)(k & 0xFFFFu);
            if (idx >= NA) idx = NA - 1;
            sbox[r] = boxes[idx];
            kb[r] = ((u32)(k >> 16) > 0x007FFFFFu) ? 1 : 0;
        } else { sbox[r] = make_float4(0, 0, 0, 0); kb[r] = 0; }
    }
    __syncthreads();
    for (int r = tid; r < 2048; r += 256)
        sorted[(size_t)b * 2048 + r] = sbox[r];
    if (tid < 64) {
        u32 v = 0;
#pragma unroll
        for (int bit = 0; bit < 32; ++bit)
            v |= ((u32)kb[tid * 32 + bit]) << bit;
        validw[b * 64 + tid] = v;
    }
}

// ---------------------------------------------------------------------------
// Kernel 5: all-pairs IoU suppression bitmask. grid (8, 16), block 256.
// ---------------------------------------------------------------------------
__global__ __launch_bounds__(256) void mask_k(const float4* __restrict__ sorted,
                                              u32* __restrict__ rows) {
    const int b = blockIdx.x, chunk = blockIdx.y;
    const int tid = threadIdx.x;
    __shared__ float4 sbx[2048];
    __shared__ float  sar[2048];
    const float4* src = sorted + (size_t)b * 2048;
    for (int e = tid; e < 2048; e += 256) {
        float4 v = src[e];
        sbx[e] = v;
        sar[e] = __fmul_rn(__fsub_rn(v.z, v.x), __fsub_rn(v.w, v.y));
    }
    __syncthreads();
    const int i = chunk * 128 + (tid & 127);
    const int half = tid >> 7;
    const float4 bi = sbx[i];
    const float  ai = sar[i];
    u32* rp = rows + ((size_t)b * 2048 + i) * 64;
    for (int jw = half * 32; jw < half * 32 + 32; ++jw) {
        u32 bits = 0;
#pragma unroll
        for (int jb = 0; jb < 32; ++jb) {
            int j = jw * 32 + jb;
            float4 bj = sbx[j];
            float lx = fmaxf(bi.x, bj.x), ly = fmaxf(bi.y, bj.y);
            float rx = fminf(bi.z, bj.z), ry = fminf(bi.w, bj.w);
            float wv = fmaxf(__fsub_rn(rx, lx), 0.f);
            float hv = fmaxf(__fsub_rn(ry, ly), 0.f);
            float inter = __fmul_rn(wv, hv);
            float den = __fadd_rn(__fsub_rn(__fadd_rn(ai, sar[j]), inter), 1e-9f);
            float iou = __fdiv_rn(inter, den);
            if (iou > 0.7f) bits |= (1u << jb);
        }
        rp[jw] = bits;
    }
}

// ---------------------------------------------------------------------------
// Kernel 6: greedy bit-sweep (one wave per image, prefetched rows), then
// parallel rank/compact. grid (8), block 64.
// ---------------------------------------------------------------------------
__global__ __launch_bounds__(64) void sweep_k(const u32* __restrict__ rows,
                                              const u32* __restrict__ validw,
                                              const float4* __restrict__ sorted,
                                              float* __restrict__ out) {
    const int b = blockIdx.x;
    const int lane = threadIdx.x;
    const u32* R = rows + (size_t)b * 2048 * 64;
    u32 vbits = validw[b * 64 + lane];
    u32 acc = 0, kw = 0;
    u32 pf[8];
#pragma unroll
    for (int s = 0; s < 8; ++s) pf[s] = R[(size_t)s * 64 + lane];
    for (int ib = 0; ib < PRE_NMS; ib += 8) {
#pragma unroll
        for (int s = 0; s < 8; ++s) {
            const int i = ib + s;
            u32 aw = (u32)__shfl((int)acc,   i >> 5, 64);
            u32 vw = (u32)__shfl((int)vbits, i >> 5, 64);
            bool live = ((vw >> (i & 31)) & 1u) && !((aw >> (i & 31)) & 1u);
            if (live) {
                acc |= pf[s];
                if (lane == (i >> 5)) kw |= 1u << (i & 31);
            }
            pf[s] = R[(size_t)(i + 8) * 64 + lane];   // i+8 <= 2007 < 2048
        }
    }
    __shared__ u32 kws[64];
    __shared__ int pfx[65];
    kws[lane] = kw;
    __syncthreads();
    if (lane == 0) {
        int s = 0;
        for (int w = 0; w < 64; ++w) { pfx[w] = s; s += __popc(kws[w]); }
        pfx[64] = s;
    }
    __syncthreads();
    float* rois = out + ROIS_OFF + (size_t)b * POST_NMS * 4;
    const float4* src = sorted + (size_t)b * 2048;
    for (int i2 = lane; i2 < 2048; i2 += 64) {
        int w = i2 >> 5; u32 word = kws[w];
        if ((word >> (i2 & 31)) & 1u) {
            int rank = pfx[w] + __popc(word & ((1u << (i2 & 31)) - 1u));
            if (rank < POST_NMS) {
                float4 v = src[i2];
                *(float4*)(rois + rank * 4) = v;
            }
        }
    }
    int kc = pfx[64]; if (kc > POST_NMS) kc = POST_NMS;
    for (int j = kc + lane; j < POST_NMS; j += 64)
        *(float4*)(rois + j * 4) = make_float4(0, 0, 0, 0);
    float* rip = out + IDX_OFF + (size_t)b * POST_NMS;
    for (int j = lane; j < POST_NMS; j += 64) rip[j] = (float)b;
}

// ---------------------------------------------------------------------------
extern "C" void kernel_launch(void* const* d_in, const int* in_sizes, int n_in,
                              void* d_out, int out_size, void* d_ws, size_t ws_size,
                              hipStream_t stream) {
    const float* feat    = (const float*)d_in[0];
    const float* conv1_w = (const float*)d_in[1];
    const float* conv1_b = (const float*)d_in[2];
    const float* cls_w   = (const float*)d_in[3];
    const float* cls_b   = (const float*)d_in[4];
    const float* loc_w   = (const float*)d_in[5];
    const float* loc_b   = (const float*)d_in[6];
    const int*   ih      = (const int*)d_in[7];
    const int*   iw      = (const int*)d_in[8];
    float* out = (float*)d_out;

    // ws layout: R7/R8's proven 71.2 MB envelope.
    //   conv_ws  : 8*512*4096 f32 = 67,108,864 B  (front 4.5 MB re-aliased by
    //              rows/sorted/valid AFTER head_k — stream-ordered safe)
    //   boxes_ws : 8*36864*4 f32  =  4,718,592 B
    //   keys_ws  : 8*36864 u64    =  2,359,296 B
    //   wt_ws    : 512*56 f32     =    114,688 B
    float* conv_ws  = (float*)d_ws;
    float* boxes_ws = conv_ws + (size_t)B_ * C_ * HW_;
    u64*   keys_ws  = (u64*)(boxes_ws + (size_t)B_ * NA * 4);
    float* wt_ws    = (float*)(keys_ws + (size_t)B_ * NA);
    u32*    rows_ws   = (u32*)d_ws;                                      // alias
    float4* sorted_ws = (float4*)((char*)d_ws + (4u << 20));             // alias
    u32*    valid_ws  = (u32*)((char*)d_ws + (4u << 20) + (512u << 10)); // alias

    hipLaunchKernelGGL(wprep_k, dim3(112), dim3(256), 0, stream, loc_w, cls_w, wt_ws);
    hipLaunchKernelGGL(conv3x3_k, dim3(16, 16, 8), dim3(256), 0, stream,
                       feat, conv1_w, conv1_b, conv_ws);
    hipLaunchKernelGGL(head_k, dim3(512), dim3(256), 0, stream,
                       conv_ws, wt_ws, loc_b, cls_b, out);
    hipLaunchKernelGGL(decode_k, dim3(8, 144), dim3(256), 0, stream,
                       ih, iw, out, boxes_ws, keys_ws);
    hipLaunchKernelGGL(select_k, dim3(8), dim3(256), 0, stream,
                       keys_ws, boxes_ws, sorted_ws, valid_ws);
    hipLaunchKernelGGL(mask_k, dim3(8, 16), dim3(256), 0, stream,
                       sorted_ws, rows_ws);
    hipLaunchKernelGGL(sweep_k, dim3(8), dim3(64), 0, stream,
                       rows_ws, valid_ws, sorted_ws, out);
}